// Round 13
// baseline (1736.589 us; speedup 1.0000x reference)
//
#include <hip/hip_runtime.h>

// ---------------------------------------------------------------------------
// Self_RNN forward, MI355X — 2-step algebraic unroll (one sync hop / 2 steps).
//   Basis per block (t even): V=h@Wrv, P=XV[t-1], C=XV[t].
//   h(t+1) = a0*V + a1*P + a2*C  (a = softmax(s0,s1,s2) of step t)
//   h(t+2) = a0'*(a0*Y2 + a1*P@Wrv + a2*C@Wrv) + a1'*C + a2'*XV[t+1]
//     Y2 = h@W2 (W2=Wrv@Wrv); scores(t+1) are bilinear forms in the basis:
//     s1' = a0*(V.G[t]) + a1*(P.G[t]) + a2*(C.G[t]);  s2' same with G[t+1]
//     s0' = sum_ij a_i a_j T_ij,  T_ij = (v_i@Wkq).v_j ; V@Wkq = h@W2k.
//   P.G / C.G precomputed (SD); T/V.G terms published as scalar partials.
// R13 fixes vs R12: (1) LDS weight preload now fills FULL 1024B rows
// (k<32, was k<8 => 3/4 of wlds was uninitialized garbage -> NaN);
// (2) C-basis rows init to XV[0] (with barrier between zero-fill and
// XOR-addressed overwrite); (3) compact ws layout (~67.4 MiB peak).
// ---------------------------------------------------------------------------

typedef _Float16 f16;
typedef _Float16 half8 __attribute__((ext_vector_type(8)));
typedef _Float16 h2 __attribute__((ext_vector_type(2)));
typedef float floatx4 __attribute__((ext_vector_type(4)));
typedef unsigned long long u64;

#define AM_F32 0
#define AM_F16 1
#define BM_NN_F32 0
#define BM_BT_F16 1
#define BM_BT_F32 2

#if defined(__has_builtin)
#if __has_builtin(__builtin_amdgcn_fdot2)
#define HAS_FDOT2 1
#endif
#endif

__device__ inline float dot2f(h2 a, h2 b, float c) {
#ifdef HAS_FDOT2
  return __builtin_amdgcn_fdot2(a, b, c, false);
#else
  return c + (float)a[0] * (float)b[0] + (float)a[1] * (float)b[1];
#endif
}

// C[M,N] = A[M,K] @ B ; 128x128 tile, BK=32, 4 waves, MFMA f16.
template<int AMODE, int BMODE, int CT>
__global__ __launch_bounds__(256)
void gemm128(const void* __restrict__ Ap, const void* __restrict__ Bp,
             f16* __restrict__ C, int K, int ldbnn, long ldc, long coff,
             int ntiles) {
  __shared__ f16 Al[128 * 32];
  __shared__ f16 Bl[128 * 32];
  const int tid = threadIdx.x;
  const int lane = tid & 63;
  const int wid = tid >> 6;
  const int wr = wid >> 1, wc = wid & 1;
  const int mt = blockIdx.x / ntiles, nt = blockIdx.x % ntiles;
  const long m0 = (long)mt * 128, n0 = (long)nt * 128;

  floatx4 acc[4][4];
#pragma unroll
  for (int m = 0; m < 4; ++m)
#pragma unroll
    for (int n = 0; n < 4; ++n) acc[m][n] = (floatx4){0.f, 0.f, 0.f, 0.f};

  for (int k0 = 0; k0 < K; k0 += 32) {
    __syncthreads();
#pragma unroll
    for (int i = 0; i < 2; ++i) {
      const int slot = i * 256 + tid;
      const int row = slot >> 2;
      const int kc = (slot & 3) * 8;
      if constexpr (AMODE == AM_F16) {
        const f16* Ag = (const f16*)Ap;
        half8 v = *(const half8*)(Ag + (m0 + row) * (long)K + k0 + kc);
        *(half8*)(Al + slot * 8) = v;
      } else {
        const float* Ag = (const float*)Ap;
        const float* p = Ag + (m0 + row) * (long)K + k0 + kc;
        float4 v0 = *(const float4*)(p);
        float4 v1 = *(const float4*)(p + 4);
        half8 h;
        h[0] = (f16)v0.x; h[1] = (f16)v0.y; h[2] = (f16)v0.z; h[3] = (f16)v0.w;
        h[4] = (f16)v1.x; h[5] = (f16)v1.y; h[6] = (f16)v1.z; h[7] = (f16)v1.w;
        *(half8*)(Al + slot * 8) = h;
      }
    }
    if constexpr (BMODE == BM_NN_F32) {
      const float* Bg = (const float*)Bp;
      const int nn = tid & 127;
      const int kh = (tid >> 7) * 16;
#pragma unroll
      for (int j = 0; j < 16; j += 2) {
        float b0 = Bg[(long)(k0 + kh + j) * ldbnn + n0 + nn];
        float b1 = Bg[(long)(k0 + kh + j + 1) * ldbnn + n0 + nn];
        h2 hv; hv[0] = (f16)b0; hv[1] = (f16)b1;
        *(h2*)(Bl + nn * 32 + kh + j) = hv;
      }
    } else {
#pragma unroll
      for (int i = 0; i < 2; ++i) {
        const int slot = i * 256 + tid;
        const int row = slot >> 2;
        const int kc = (slot & 3) * 8;
        if constexpr (BMODE == BM_BT_F16) {
          const f16* Bg = (const f16*)Bp;
          half8 v = *(const half8*)(Bg + (n0 + row) * (long)K + k0 + kc);
          *(half8*)(Bl + slot * 8) = v;
        } else {
          const float* Bg = (const float*)Bp;
          const float* p = Bg + (n0 + row) * (long)K + k0 + kc;
          float4 v0 = *(const float4*)(p);
          float4 v1 = *(const float4*)(p + 4);
          half8 h;
          h[0] = (f16)v0.x; h[1] = (f16)v0.y; h[2] = (f16)v0.z; h[3] = (f16)v0.w;
          h[4] = (f16)v1.x; h[5] = (f16)v1.y; h[6] = (f16)v1.z; h[7] = (f16)v1.w;
          *(half8*)(Bl + slot * 8) = h;
        }
      }
    }
    __syncthreads();
    const int frow = lane & 15;
    const int fkc = (lane >> 4) * 8;
    half8 af[4], bf[4];
#pragma unroll
    for (int m = 0; m < 4; ++m)
      af[m] = *(const half8*)(Al + (wr * 64 + m * 16 + frow) * 32 + fkc);
#pragma unroll
    for (int n = 0; n < 4; ++n)
      bf[n] = *(const half8*)(Bl + (wc * 64 + n * 16 + frow) * 32 + fkc);
#pragma unroll
    for (int m = 0; m < 4; ++m)
#pragma unroll
      for (int n = 0; n < 4; ++n)
        acc[m][n] = __builtin_amdgcn_mfma_f32_16x16x32_f16(af[m], bf[n],
                                                           acc[m][n], 0, 0, 0);
  }
  const int crow = (lane >> 4) * 4;
  const int ccol = lane & 15;
#pragma unroll
  for (int m = 0; m < 4; ++m)
#pragma unroll
    for (int n = 0; n < 4; ++n)
#pragma unroll
      for (int r = 0; r < 4; ++r) {
        long row = m0 + wr * 64 + m * 16 + crow + r;
        long col = n0 + wc * 64 + n * 16 + ccol;
        if constexpr (CT)
          C[(coff + col) * ldc + row] = (f16)acc[m][n][r];
        else
          C[row * ldc + coff + col] = (f16)acc[m][n][r];
      }
}

// SD[b][t_even][4] = {XV[t-1].G[t], XV[t].G[t], XV[t-1].G[t+1], XV[t].G[t+1]}
__global__ void sd_kernel(const f16* __restrict__ GXV, float* __restrict__ SD) {
  const int b = blockIdx.x >> 8;
  const int te = (blockIdx.x & 255) << 1;
  const int tid = threadIdx.x;
  const int lane = tid & 63, wid = tid >> 6;
  __shared__ float red[4][4];
  const f16* rc = GXV + ((size_t)b * 512 + te) * 1024;
  h2 gt = *(const h2*)(rc + 2 * tid);
  h2 g1 = *(const h2*)(rc + 1024 + 2 * tid);
  h2 xc = *(const h2*)(rc + 512 + 2 * tid);
  h2 xp; xp[0] = (f16)0.f; xp[1] = (f16)0.f;
  if (te > 0) xp = *(const h2*)(rc - 1024 + 512 + 2 * tid);
  float p0 = dot2f(xp, gt, 0.f), p1 = dot2f(xc, gt, 0.f);
  float p2 = dot2f(xp, g1, 0.f), p3 = dot2f(xc, g1, 0.f);
#pragma unroll
  for (int off = 32; off > 0; off >>= 1) {
    p0 += __shfl_down(p0, off); p1 += __shfl_down(p1, off);
    p2 += __shfl_down(p2, off); p3 += __shfl_down(p3, off);
  }
  if (lane == 0) { red[wid][0] = p0; red[wid][1] = p1; red[wid][2] = p2; red[wid][3] = p3; }
  __syncthreads();
  if (tid < 4)
    SD[((size_t)b * 512 + te) * 4 + tid] =
        red[0][tid] + red[1][tid] + red[2][tid] + red[3][tid];
}

// zero tagged buffer: 122880 u64. MUST run every launch.
__global__ void zero_ybuf(u64* ybuf) {
  ybuf[(size_t)blockIdx.x * 256 + threadIdx.x] = 0ull;
}

// yVec[16grp][2par][3vec][4ch][256 pairs]; sblk[16grp][2par][48][16 slices].
__global__ __launch_bounds__(256, 1)
void seq_kernel(const f16* __restrict__ Wt4, const f16* __restrict__ GXV,
                const float* __restrict__ SD, u64* __restrict__ ybuf,
                float* __restrict__ out) {
  const int wg = blockIdx.x;
  const int grp = wg & 15;
  const int s = wg >> 4;
  const int tid = threadIdx.x;
  const int lane = tid & 63;
  const int wid = tid >> 6;
  const int rowgrp = lane >> 4;

  __shared__ __align__(16) char wlds[128 * 1024];  // [4mat][32col][512k] f16 XOR
  __shared__ __align__(16) char apkb[16 * 1024];   // A rows: 0-3 h,4-7 P,8-11 C
  __shared__ __align__(16) floatx4 ofr4[5 * 32];   // [vec][col] x 4 chains
  __shared__ float swred[4][8];
  __shared__ float sldr[48];

  // ---- preload 4 weight slices (32 cols each) — FULL rows (fix #1) ----
  {
    const int r = tid >> 1;               // 0..127 = mat*32 + lc
    const int lc = r & 31;
    const int seg = (tid & 1) * 512;      // two threads cover 1024B row
    const unsigned key = ((unsigned)(lc & 7)) << 4;
    const f16* src = Wt4 + (((size_t)(r >> 5) * 512) + s * 32 + lc) * 512;
#pragma unroll
    for (int k = 0; k < 32; ++k) {
      half8 v = *(const half8*)((const char*)src + seg + k * 16);
      *(half8*)(wlds + r * 1024 + ((unsigned)(seg + k * 16) ^ key)) = v;
    }
  }
#pragma unroll
  for (int i = 0; i < 4; ++i)
    *(floatx4*)(apkb + tid * 64 + i * 16) = (floatx4){0.f, 0.f, 0.f, 0.f};
  __syncthreads();  // zero-fill visible before XOR-addressed overwrite (fix #2)
  {
    // C-basis rows (8-11) start as XV[0]
#pragma unroll
    for (int c4 = 0; c4 < 4; ++c4) {
      h2 xc0 = *(const h2*)(GXV + (((size_t)(grp * 4 + c4)) * 512) * 1024 + 512 + 2 * tid);
      *(h2*)(apkb + (8 + c4) * 1024 +
             (((unsigned)(4 * tid)) ^ ((((unsigned)(8 + c4)) & 7) << 4))) = xc0;
    }
  }
  __syncthreads();

  const float scale = 0.04419417382415922f;  // 1/sqrt(512)
  u64* const yVec = ybuf;
  u64* const sblk = ybuf + 98304;

  const int arow = lane & 15;
  const unsigned abkey = ((unsigned)(arow & 7)) << 4;
  const int kseg = (lane >> 4) * 16;

  for (int nb = 0; nb < 256; ++nb) {
    const int t = nb * 2;
    const int par = nb & 1;
    const u64 tagw = ((u64)(unsigned)(nb + 1)) << 32;

    // ---- A. hoisted per-u-pair global loads ----
    h2 gm1[4], gt[4], xv1[4], xv2[4];
#pragma unroll
    for (int c4 = 0; c4 < 4; ++c4) {
      const f16* rc = GXV + (((size_t)(grp * 4 + c4)) * 512 + t) * 1024;
      gm1[c4] = *(const h2*)(rc + (t > 0 ? -1024 : 0) + 2 * tid);  // G[t-1] (h=0 at t=0)
      gt[c4] = *(const h2*)(rc + 2 * tid);                         // G[t]
      xv1[c4] = *(const h2*)(rc + 1024 + 512 + 2 * tid);           // XV[t+1]
      xv2[c4] = *(const h2*)(rc + (t < 510 ? 2048 : 1024) + 512 + 2 * tid);  // XV[t+2] clamp
    }

    // ---- B. MFMA: wave w -> matrix w (0=Wkq,1=Wrv,2=W2,3=W2k), A=[h|P|C|0] --
    floatx4 acc[2];
    acc[0] = (floatx4){0.f, 0.f, 0.f, 0.f};
    acc[1] = (floatx4){0.f, 0.f, 0.f, 0.f};
#pragma unroll
    for (int ks = 0; ks < 16; ++ks) {
      const unsigned ko = (unsigned)(ks * 64 + kseg);
      half8 av = *(const half8*)(apkb + arow * 1024 + (ko ^ abkey));
#pragma unroll
      for (int nt = 0; nt < 2; ++nt) {
        half8 bv = *(const half8*)(wlds + (wid * 32 + nt * 16 + arow) * 1024 + (ko ^ abkey));
        acc[nt] = __builtin_amdgcn_mfma_f32_16x16x32_f16(av, bv, acc[nt], 0, 0, 0);
      }
    }

    // ---- C. early vector publish (Y2, P@Wrv, C@Wrv) + ofrag stash ----
    if (wid == 1 || wid == 2) {
#pragma unroll
      for (int r = 0; r < 4; ++r)
#pragma unroll
        for (int nt = 0; nt < 2; ++nt) {
          float v = acc[nt][r];
          float vp = __shfl_xor(v, 1);
          int vec = (wid == 2) ? (rowgrp == 0 ? 0 : -1)
                               : (rowgrp == 1 ? 1 : (rowgrp == 2 ? 2 : -1));
          if (vec >= 0 && !(lane & 1)) {
            h2 pk; pk[0] = (f16)v; pk[1] = (f16)vp;
            unsigned lo; __builtin_memcpy(&lo, &pk, 4);
            __hip_atomic_store(
                yVec + ((((size_t)grp * 2 + par) * 3 + vec) * 4 + r) * 256 +
                    s * 16 + nt * 8 + ((lane & 15) >> 1),
                tagw | (u64)lo, __ATOMIC_RELAXED, __HIP_MEMORY_SCOPE_AGENT);
          }
        }
    }
    {
      int vec = -1;
      if (wid == 0 && rowgrp < 3) vec = rowgrp;       // 0=hq,1=PK,2=CK
      else if (wid == 1 && rowgrp == 0) vec = 3;      // Vh
      else if (wid == 3 && rowgrp == 0) vec = 4;      // hk2
      if (vec >= 0) {
#pragma unroll
        for (int nt = 0; nt < 2; ++nt)
          ofr4[vec * 32 + nt * 16 + (lane & 15)] = acc[nt];
      }
    }
    __syncthreads();  // (1)

    // ---- D. scalar partials (12 types x 4 chains; tid<192) + publish ----
    if (tid < 192) {
      const int q = tid >> 2;
      const int type = q >> 2;
      const int ch = q & 3;
      const int c0 = (tid & 3) * 8;
      const int gbase = s * 32 + c0;
      const int avecs[12] = {0, 3, 3, 4, 4, 4, 1, 2, 1, 1, 2, 2};
      const int av = avecs[type];
      const float* ofr = (const float*)ofr4;
      float bv[8];
      if (type == 0) {
        half8 h8 = *(const half8*)(apkb + ch * 1024 +
                                   (((unsigned)(2 * gbase)) ^ ((unsigned)ch << 4)));
#pragma unroll
        for (int j = 0; j < 8; ++j) bv[j] = (float)h8[j];
      } else if (type == 1 || type == 2) {
        const f16* g = GXV + (((size_t)(grp * 4 + ch)) * 512 + t + (type - 1)) * 1024 + gbase;
        half8 g8 = *(const half8*)g;
#pragma unroll
        for (int j = 0; j < 8; ++j) bv[j] = (float)g8[j];
      } else if (type == 3 || type == 6 || type == 7) {
#pragma unroll
        for (int j = 0; j < 8; ++j) bv[j] = ofr[(3 * 32 + c0 + j) * 4 + ch];
      } else if (type == 4 || type == 8 || type == 10) {
        half8 h8 = *(const half8*)(apkb + (4 + ch) * 1024 +
                                   (((unsigned)(2 * gbase)) ^ (((unsigned)(4 + ch) & 7) << 4)));
#pragma unroll
        for (int j = 0; j < 8; ++j) bv[j] = (float)h8[j];
      } else {  // 5, 9, 11 -> C row
        half8 h8 = *(const half8*)(apkb + (8 + ch) * 1024 +
                                   (((unsigned)(2 * gbase)) ^ (((unsigned)(8 + ch) & 7) << 4)));
#pragma unroll
        for (int j = 0; j < 8; ++j) bv[j] = (float)h8[j];
      }
      float p = 0.f;
#pragma unroll
      for (int j = 0; j < 8; ++j) p += ofr[(av * 32 + c0 + j) * 4 + ch] * bv[j];
      p += __shfl_down(p, 1);
      p += __shfl_down(p, 2);
      if ((tid & 3) == 0)
        __hip_atomic_store(sblk + (((size_t)grp * 2 + par) * 48 + q) * 16 + s,
                           tagw | (u64)__float_as_uint(p), __ATOMIC_RELAXED,
                           __HIP_MEMORY_SCOPE_AGENT);
    }

    // ---- E. s1(t)/s2(t) local dot partials ----
    {
      float pr[8];
#pragma unroll
      for (int c4 = 0; c4 < 4; ++c4) {
        h2 hv = *(const h2*)(apkb + c4 * 1024 +
                             (((unsigned)(4 * tid)) ^ (((unsigned)c4) << 4)));
        pr[2 * c4] = dot2f(gm1[c4], hv, 0.f);
        pr[2 * c4 + 1] = dot2f(gt[c4], hv, 0.f);
      }
#pragma unroll
      for (int off = 32; off > 0; off >>= 1)
#pragma unroll
        for (int i = 0; i < 8; ++i) pr[i] += __shfl_down(pr[i], off);
      if (lane == 0) {
#pragma unroll
        for (int i = 0; i < 8; ++i) swred[wid][i] = pr[i];
      }
    }

    // ---- F. poll: 12 vector pair-words; tid<48 also 16 scalar words ----
    const u64* vb = yVec + (((size_t)grp * 2 + par) * 12) * 256 + tid;
    const u64* sb = sblk + (((size_t)grp * 2 + par) * 48 + tid) * 16;
    u64 vv[12];
    u64 sv[16];
    for (;;) {
      bool ok = true;
#pragma unroll
      for (int v = 0; v < 12; ++v) {
        vv[v] = __hip_atomic_load(vb + v * 256, __ATOMIC_RELAXED,
                                  __HIP_MEMORY_SCOPE_AGENT);
        ok = ok && (vv[v] >= tagw);
      }
      if (tid < 48) {
#pragma unroll
        for (int i = 0; i < 16; ++i) {
          sv[i] = __hip_atomic_load(sb + i, __ATOMIC_RELAXED,
                                    __HIP_MEMORY_SCOPE_AGENT);
          ok = ok && (sv[i] >= tagw);
        }
      }
      if (ok) break;
      __builtin_amdgcn_s_sleep(1);
    }
    if (tid < 48) {
      float ssum = 0.f;
#pragma unroll
      for (int i = 0; i < 16; ++i) ssum += __uint_as_float((unsigned)sv[i]);
      sldr[tid] = ssum;
    }
    __syncthreads();  // (2)

    // ---- G. coefficients + h(t+2) update ----
#pragma unroll
    for (int c4 = 0; c4 < 4; ++c4) {
      const float sv0 = sldr[c4] * scale;
      const float sv1 = (swred[0][2 * c4] + swred[1][2 * c4] + swred[2][2 * c4] +
                         swred[3][2 * c4]) * scale;
      const float sv2 = (swred[0][2 * c4 + 1] + swred[1][2 * c4 + 1] +
                         swred[2][2 * c4 + 1] + swred[3][2 * c4 + 1]) * scale;
      float mx = fmaxf(sv0, fmaxf(sv1, sv2));
      float e0 = __expf(sv0 - mx), e1 = __expf(sv1 - mx), e2 = __expf(sv2 - mx);
      float inv = 1.f / (e0 + e1 + e2);
      const float a0 = e0 * inv, a1 = e1 * inv, a2 = e2 * inv;

      const float4 sd = *(const float4*)(SD + (((size_t)(grp * 4 + c4)) * 512 + t) * 4);
      const float s1n = (a0 * sldr[4 + c4] + a1 * sd.x + a2 * sd.y) * scale;
      const float s2n = (a0 * sldr[8 + c4] + a1 * sd.z + a2 * sd.w) * scale;
      const float s0n =
          (a0 * a0 * sldr[12 + c4] + a0 * a1 * (sldr[16 + c4] + sldr[24 + c4]) +
           a0 * a2 * (sldr[20 + c4] + sldr[28 + c4]) + a1 * a1 * sldr[32 + c4] +
           a1 * a2 * (sldr[36 + c4] + sldr[40 + c4]) + a2 * a2 * sldr[44 + c4]) *
          scale;
      mx = fmaxf(s0n, fmaxf(s1n, s2n));
      e0 = __expf(s0n - mx); e1 = __expf(s1n - mx); e2 = __expf(s2n - mx);
      inv = 1.f / (e0 + e1 + e2);
      const float b0 = e0 * inv, b1 = e1 * inv, b2 = e2 * inv;
      const float cA = b0 * a0, cB = b0 * a1, cC = b0 * a2;

      unsigned lo;
      lo = (unsigned)vv[c4];      h2 y2; __builtin_memcpy(&y2, &lo, 4);
      lo = (unsigned)vv[4 + c4];  h2 pr_; __builtin_memcpy(&pr_, &lo, 4);
      lo = (unsigned)vv[8 + c4];  h2 cr_; __builtin_memcpy(&cr_, &lo, 4);
      h2 xvt = *(const h2*)(apkb + (8 + c4) * 1024 +
                            (((unsigned)(4 * tid)) ^ ((((unsigned)(8 + c4)) & 7) << 4)));
      float hn0 = cA * (float)y2[0] + cB * (float)pr_[0] + cC * (float)cr_[0] +
                  b1 * (float)xvt[0] + b2 * (float)xv1[c4][0];
      float hn1 = cA * (float)y2[1] + cB * (float)pr_[1] + cC * (float)cr_[1] +
                  b1 * (float)xvt[1] + b2 * (float)xv1[c4][1];
      h2 hn; hn[0] = (f16)hn0; hn[1] = (f16)hn1;
      *(h2*)(apkb + c4 * 1024 + (((unsigned)(4 * tid)) ^ (((unsigned)c4) << 4))) = hn;
      *(h2*)(apkb + (4 + c4) * 1024 +
             (((unsigned)(4 * tid)) ^ ((((unsigned)(4 + c4)) & 7) << 4))) = xv1[c4];
      *(h2*)(apkb + (8 + c4) * 1024 +
             (((unsigned)(4 * tid)) ^ ((((unsigned)(8 + c4)) & 7) << 4))) = xv2[c4];
      if (nb == 255 && s == 0) {
        float* ob = out + ((size_t)grp * 4 + c4) * 512 + 2 * tid;
        ob[0] = hn0; ob[1] = hn1;
      }
    }
    __syncthreads();  // (3)
  }
}

extern "C" void kernel_launch(void* const* d_in, const int* in_sizes, int n_in,
                              void* d_out, int out_size, void* d_ws,
                              size_t ws_size, hipStream_t stream) {
  const float* x = (const float*)d_in[0];
  const float* Wq = (const float*)d_in[1];
  const float* Wk = (const float*)d_in[2];
  const float* Wv = (const float*)d_in[3];
  const float* Wrec = (const float*)d_in[4];
  float* out = (float*)d_out;

  char* ws = (char*)d_ws;
  // Compact layout (fix #3). Live ranges guarantee no overlap-in-time:
  //   WrvRM @ GXV start (dead before GXV gemms); WgT reuses Wrq's slot
  //   (Wrq dead after mat0); SD overlays Wrk (dead after WgT gemm);
  //   ybuf overlays Wrq/WgT region (dead before zero_ybuf).
  f16* GXV = (f16*)ws;                          // [32768][1024] = 64 MiB
  f16* Wt4 = (f16*)(ws + 67108864);             // 4 x [512][512]^T = 2 MiB
  f16* Wrk = (f16*)(ws + 69206016);             // 512 KiB (temp)
  f16* Wrq = (f16*)(ws + 69730304);             // 512 KiB (temp)
  f16* WrvRM = (f16*)ws;                        // temp, overlays GXV rows 0-255
  f16* WgT = (f16*)(ws + 69730304);             // temp, reuses Wrq slot
  float* SD = (float*)(ws + 69206016);          // 512 KiB, overlays Wrk
  u64* ybuf = (u64*)(ws + 69730304);            // 960 KiB, overlays Wrq/WgT
  f16* mat0 = Wt4;                 // Wkq^T
  f16* mat1 = Wt4 + 262144;        // Wrv^T
  f16* mat2 = Wt4 + 524288;        // W2^T
  f16* mat3 = Wt4 + 786432;        // W2k^T

  gemm128<AM_F32, BM_NN_F32, 0><<<16, 256, 0, stream>>>(Wrec, Wk, Wrk, 512, 512, 512, 0, 4);
  gemm128<AM_F32, BM_NN_F32, 0><<<16, 256, 0, stream>>>(Wrec, Wq, Wrq, 512, 512, 512, 0, 4);
  gemm128<AM_F32, BM_NN_F32, 1><<<16, 256, 0, stream>>>(Wrec, Wv, mat1, 512, 512, 512, 0, 4);
  gemm128<AM_F32, BM_NN_F32, 0><<<16, 256, 0, stream>>>(Wrec, Wv, WrvRM, 512, 512, 512, 0, 4);
  gemm128<AM_F16, BM_BT_F16, 1><<<16, 256, 0, stream>>>(Wrk, Wrq, mat0, 512, 0, 512, 0, 4);
  gemm128<AM_F16, BM_BT_F16, 1><<<16, 256, 0, stream>>>(WrvRM, mat1, mat2, 512, 0, 512, 0, 4);
  gemm128<AM_F16, BM_BT_F16, 1><<<16, 256, 0, stream>>>(WrvRM, mat0, mat3, 512, 0, 512, 0, 4);
  gemm128<AM_F16, BM_BT_F32, 0><<<16, 256, 0, stream>>>(Wrk, Wq, WgT, 512, 0, 512, 0, 4);
  gemm128<AM_F32, BM_BT_F16, 0><<<1024, 256, 0, stream>>>(x, WgT, GXV, 512, 0, 1024, 0, 4);
  gemm128<AM_F32, BM_NN_F32, 0><<<1024, 256, 0, stream>>>(x, Wv, GXV, 512, 512, 1024, 512, 4);

  sd_kernel<<<16384, 256, 0, stream>>>(GXV, SD);
  zero_ybuf<<<480, 256, 0, stream>>>(ybuf);

  const f16* Wt4C = Wt4; const f16* GXVC = GXV; const float* SDC = SD;
  void* args[] = {(void*)&Wt4C, (void*)&GXVC, (void*)&SDC, (void*)&ybuf, (void*)&out};
  dim3 grid(256), block(256);
  if (hipLaunchCooperativeKernel((const void*)seq_kernel, grid, block, args, 0,
                                 stream) != hipSuccess) {
    seq_kernel<<<grid, block, 0, stream>>>(Wt4C, GXVC, SDC, ybuf, out);
  }
}